// Round 1
// baseline (908.983 us; speedup 1.0000x reference)
//
#include <hip/hip_runtime.h>
#include <hip/hip_bf16.h>
#include <stdint.h>
#include <stddef.h>

typedef __bf16 bf16;
typedef __bf16 bf16x4 __attribute__((ext_vector_type(4)));
typedef __bf16 bf16x8 __attribute__((ext_vector_type(8)));
typedef float  f32x4  __attribute__((ext_vector_type(4)));

__device__ __forceinline__ void async16(const void* src, void* dst) {
    __builtin_amdgcn_global_load_lds(
        (__attribute__((address_space(1))) void*)(void*)(src),
        (__attribute__((address_space(3))) void*)(dst),
        16, 0, 0);
}

#define MEMFENCE asm volatile("" ::: "memory")

// ---------------------------------------------------------------------------
// Kernel 0: f32 -> bf16 weight conversion (n divisible by 4)
// ---------------------------------------------------------------------------
__global__ __launch_bounds__(256)
void f2b(const float* __restrict__ src, bf16* __restrict__ dst, int n)
{
    const int i = (blockIdx.x * 256 + threadIdx.x) * 4;
    if (i < n) {
        f32x4 c = *(const f32x4*)(src + i);
        bf16x4 o;
        #pragma unroll
        for (int q = 0; q < 4; ++q) o[q] = (bf16)c[q];
        *(bf16x4*)(dst + i) = o;
    }
}

// ---------------------------------------------------------------------------
// Kernel 1: LN over x rows (768, f32 in) + window permutation -> bf16 Y.
// ---------------------------------------------------------------------------
__global__ __launch_bounds__(256)
void ln1_win(const float* __restrict__ x, const float* __restrict__ g,
             const float* __restrict__ b, bf16* __restrict__ Y)
{
    const int row  = blockIdx.x * 4 + (threadIdx.x >> 6);
    const int lane = threadIdx.x & 63;
    const float* xr = x + (size_t)row * 768;
    float v[12];
    float sum = 0.f, ssq = 0.f;
    #pragma unroll
    for (int j = 0; j < 3; ++j) {
        f32x4 c = *(const f32x4*)(xr + j * 256 + lane * 4);
        #pragma unroll
        for (int q = 0; q < 4; ++q) {
            float f = c[q];
            v[j * 4 + q] = f; sum += f; ssq += f * f;
        }
    }
    #pragma unroll
    for (int d = 1; d < 64; d <<= 1) {
        sum += __shfl_xor(sum, d, 64);
        ssq += __shfl_xor(ssq, d, 64);
    }
    const float mean = sum * (1.f / 768.f);
    const float rstd = rsqrtf(ssq * (1.f / 768.f) - mean * mean + 1e-5f);
    const int bb = row >> 14;
    const int l  = row & 16383;
    const int hy = l >> 7, wx = l & 127;
    const int m  = ((bb * 256 + (hy >> 3) * 16 + (wx >> 3)) << 6)
                 + ((hy & 7) << 3) + (wx & 7);
    bf16* yr = Y + (size_t)m * 768;
    #pragma unroll
    for (int j = 0; j < 3; ++j) {
        const int c0 = j * 256 + lane * 4;
        f32x4 gg = *(const f32x4*)(g + c0);
        f32x4 bv = *(const f32x4*)(b + c0);
        bf16x4 ov;
        #pragma unroll
        for (int q = 0; q < 4; ++q)
            ov[q] = (bf16)((v[j * 4 + q] - mean) * rstd * gg[q] + bv[q]);
        *(bf16x4*)(yr + c0) = ov;
    }
}

// ---------------------------------------------------------------------------
// Kernel 1b: Gbuf[f] = Y[Smod+f] + Y[2*Smod+f]  (green+blue), f < Smod.
// Makes all GEMM A-staging a uniform global_load_lds gather.
// ---------------------------------------------------------------------------
__global__ __launch_bounds__(256)
void gsum(const bf16* __restrict__ Y, bf16* __restrict__ G, int Smod)
{
    const int i = (blockIdx.x * 256 + threadIdx.x) * 8;
    if (i < Smod) {
        bf16x8 a = *(const bf16x8*)(Y + Smod + i);
        bf16x8 c = *(const bf16x8*)(Y + 2 * Smod + i);
        bf16x8 r;
        #pragma unroll
        for (int q = 0; q < 8; ++q) r[q] = (bf16)((float)a[q] + (float)c[q]);
        *(bf16x8*)(G + i) = r;
    }
}

// ---------------------------------------------------------------------------
// GEMM: C = A @ B^T (+bias). BM=128, BN=256, BK=64, 512 threads = 8 waves
// (wm = w>>2 in {0,1} -> 64 rows; wn = w&3 -> 64 cols), 16x16x32 MFMA.
// Triple-buffered LDS (3 x 48KB = 144KB). Iteration t computes buf[t%3]
// while staging tile t+2 into buf[(t+2)%3]; iteration boundary is raw
// s_barrier with COUNTED s_waitcnt vmcnt(6) -> the 6 loads for tile t+2
// stay in flight across the barrier (T3/T4). setprio around MFMA (T5).
// XOR-swizzled LDS, staged via pre-swizzled global source (T2).
// XCD-aware 1D grid swizzle (T1): bid&7 = XCD, nbase fastest within XCD.
// AMODE 1: A gathered from (nbase<768 ? Gbuf : Y) at (m*768+k) mod Smod.
// NT: non-temporal C stores (keep L3 for A-panel re-reads).
// ---------------------------------------------------------------------------
template<int AMODE, bool BIAS, bool NT>
__global__ __launch_bounds__(512, 2)
void gemm_bt(const bf16* __restrict__ A, const bf16* __restrict__ Yg,
             const bf16* __restrict__ Gb, const bf16* __restrict__ Bm,
             const float* __restrict__ bias, bf16* __restrict__ Cm,
             int K, int ldc, int Smod, int nb_n)
{
    constexpr int ABUF = 128 * 64;
    constexpr int BBUF = 256 * 64;
    constexpr int BUF  = ABUF + BBUF;          // 24576 elem = 48KB
    __shared__ bf16 lds[3 * BUF];              // 144KB

    const int per    = gridDim.x >> 3;
    const int mchunk = per / nb_n;
    const int xcd    = blockIdx.x & 7;
    const int slot_b = blockIdx.x >> 3;
    const int mbase  = (xcd * mchunk + slot_b / nb_n) * 128;
    const int nbase  = (slot_b % nb_n) * 256;

    const int tid  = threadIdx.x;
    const int lane = tid & 63;
    const int w    = tid >> 6;
    const int quad = lane >> 4;
    const int l16  = lane & 15;
    const int wm   = (w >> 2) * 64;
    const int wn   = (w & 3) * 64;
    const int rsub = lane >> 3;
    const int slot = lane & 7;

    const bf16* Asrc = (AMODE == 1) ? ((nbase < 768) ? Gb : Yg) : A;
    const int nt = K >> 6;

    // --- staging: per K-tile, A = 2 instr/thread, B = 4 instr/thread ---
    auto stageA = [&](int t, int kt, bf16* Ab) {
        const int row = 16 * w + 8 * t + rsub;
        const int kc  = slot ^ (row & 7);
        const bf16* s;
        if (AMODE == 1) {
            int f = (mbase + row) * 768 + kt * 64 + kc * 8;
            if (f >= 2 * Smod) f -= 2 * Smod;
            else if (f >= Smod) f -= Smod;
            s = Asrc + f;
        } else {
            s = Asrc + (size_t)(mbase + row) * K + kt * 64 + kc * 8;
        }
        async16(s, Ab + (16 * w + 8 * t) * 64);   // LDS dest wave-uniform
    };
    auto stageB = [&](int t, int kt, bf16* Bb) {
        const int row = 32 * w + 8 * t + rsub;
        const int kc  = slot ^ (row & 7);
        async16(Bm + (size_t)(nbase + row) * K + kt * 64 + kc * 8,
                Bb + (32 * w + 8 * t) * 64);
    };

    const f32x4 zero = {0.f, 0.f, 0.f, 0.f};
    f32x4 acc[4][4];
    #pragma unroll
    for (int i = 0; i < 4; ++i)
        #pragma unroll
        for (int j = 0; j < 4; ++j) acc[i][j] = zero;

    auto compute = [&](int ks, const bf16* Ab, const bf16* Bb) {
        bf16x8 af[4], bfr[4];
        #pragma unroll
        for (int i = 0; i < 4; ++i) {
            const int row = wm + 16 * i + l16;
            const int sl  = (ks * 4 + quad) ^ (row & 7);
            af[i] = *(const bf16x8*)(Ab + row * 64 + sl * 8);
        }
        #pragma unroll
        for (int j = 0; j < 4; ++j) {
            const int row = wn + 16 * j + l16;
            const int sl  = (ks * 4 + quad) ^ (row & 7);
            bfr[j] = *(const bf16x8*)(Bb + row * 64 + sl * 8);
        }
        __builtin_amdgcn_s_setprio(1);
        #pragma unroll
        for (int i = 0; i < 4; ++i)
            #pragma unroll
            for (int j = 0; j < 4; ++j)
                acc[i][j] = __builtin_amdgcn_mfma_f32_16x16x32_bf16(
                    af[i], bfr[j], acc[i][j], 0, 0, 0);
        __builtin_amdgcn_s_setprio(0);
    };

    // --- prologue: stage tiles 0 and 1 (12 loads), wait for tile 0 only ---
    {
        bf16* Ab = lds;        bf16* Bb = lds + ABUF;
        stageA(0, 0, Ab); stageA(1, 0, Ab);
        stageB(0, 0, Bb); stageB(1, 0, Bb); stageB(2, 0, Bb); stageB(3, 0, Bb);
        if (nt > 1) {
            bf16* A1 = lds + BUF; bf16* B1 = lds + BUF + ABUF;
            stageA(0, 1, A1); stageA(1, 1, A1);
            stageB(0, 1, B1); stageB(1, 1, B1); stageB(2, 1, B1); stageB(3, 1, B1);
            asm volatile("s_waitcnt vmcnt(6)" ::: "memory");
        } else {
            asm volatile("s_waitcnt vmcnt(0)" ::: "memory");
        }
    }
    __builtin_amdgcn_s_barrier();
    MEMFENCE;

    int cur = 0;
    for (int t = 0; t < nt; ++t) {
        bf16* Ab = lds + cur * BUF;
        bf16* Bb = Ab + ABUF;
        const int nx = (cur + 2 >= 3) ? cur - 1 : cur + 2;
        bf16* An = lds + nx * BUF;
        bf16* Bn = An + ABUF;
        const bool pf = (t + 2 < nt);

        // phase 0: issue half of next-next tile's staging, compute ks=0
        if (pf) { stageA(0, t + 2, An); stageB(0, t + 2, Bn); stageB(1, t + 2, Bn); }
        compute(0, Ab, Bb);
        __builtin_amdgcn_s_barrier();
        MEMFENCE;

        // phase 1: other half of staging, compute ks=1
        if (pf) { stageA(1, t + 2, An); stageB(2, t + 2, Bn); stageB(3, t + 2, Bn); }
        compute(1, Ab, Bb);
        if (t < nt - 2) { asm volatile("s_waitcnt vmcnt(6)" ::: "memory"); }
        else            { asm volatile("s_waitcnt vmcnt(0)" ::: "memory"); }
        __builtin_amdgcn_s_barrier();
        MEMFENCE;

        cur = (cur + 1 == 3) ? 0 : cur + 1;
    }

    // epilogue: C/D layout col=lane&15, row=quad*4+reg
    #pragma unroll
    for (int i = 0; i < 4; ++i) {
        const int row0 = mbase + wm + 16 * i + quad * 4;
        #pragma unroll
        for (int j = 0; j < 4; ++j) {
            const int col = nbase + wn + 16 * j + l16;
            float bv = 0.f;
            if (BIAS) bv = bias[col];
            #pragma unroll
            for (int r = 0; r < 4; ++r) {
                bf16 val = (bf16)(acc[i][j][r] + bv);
                bf16* p = Cm + (size_t)(row0 + r) * ldc + col;
                if (NT) {
                    unsigned short u = __builtin_bit_cast(unsigned short, val);
                    __builtin_nontemporal_store(u, (unsigned short*)p);
                } else {
                    *p = val;
                }
            }
        }
    }
}

// ---------------------------------------------------------------------------
// Kernel 3: windowed attention, one wave per (window, head). 64x64 tiles.
// ---------------------------------------------------------------------------
__global__ __launch_bounds__(64)
void attn_win(const bf16* __restrict__ QKV, bf16* __restrict__ AOut)
{
    const int blk  = blockIdx.x;
    const int bw   = blk / 12;
    const int h    = blk % 12;
    const int lane = threadIdx.x;
    const int quad = lane >> 4;
    const int l16  = lane & 15;

    __shared__ bf16 Kt[64 * 64];
    __shared__ bf16 Vt[64 * 64];

    const size_t rowbase = (size_t)bw * 64;

    {
        const int rsub = lane >> 3;
        const int slot = lane & 7;
        #pragma unroll
        for (int t = 0; t < 8; ++t) {
            const int row = 8 * t + rsub;
            const int kcK = slot ^ (row & 7);
            async16(QKV + (rowbase + row) * 2304 + 768 + h * 64 + kcK * 8,
                    Kt + (8 * t) * 64);
            async16(QKV + (rowbase + row) * 2304 + 1536 + h * 64 + slot * 8,
                    Vt + (8 * t) * 64);
        }
    }

    bf16x8 qf[4][2];
    #pragma unroll
    for (int i = 0; i < 4; ++i)
        #pragma unroll
        for (int ks = 0; ks < 2; ++ks)
            qf[i][ks] = *(const bf16x8*)(QKV + (rowbase + 16 * i + l16) * 2304
                                         + h * 64 + ks * 32 + quad * 8);
    __syncthreads();

    const f32x4 zero = {0.f, 0.f, 0.f, 0.f};
    f32x4 s[4][4];
    #pragma unroll
    for (int i = 0; i < 4; ++i)
        #pragma unroll
        for (int j = 0; j < 4; ++j) s[i][j] = zero;

    #pragma unroll
    for (int ks = 0; ks < 2; ++ks) {
        bf16x8 kf[4];
        #pragma unroll
        for (int j = 0; j < 4; ++j) {
            const int row  = 16 * j + l16;
            const int slot = (ks * 4 + quad) ^ (row & 7);
            kf[j] = *(const bf16x8*)(Kt + row * 64 + slot * 8);
        }
        #pragma unroll
        for (int i = 0; i < 4; ++i)
            #pragma unroll
            for (int j = 0; j < 4; ++j)
                s[i][j] = __builtin_amdgcn_mfma_f32_16x16x32_bf16(
                    qf[i][ks], kf[j], s[i][j], 0, 0, 0);
    }

    float rrec[4][4];
    #pragma unroll
    for (int i = 0; i < 4; ++i) {
        #pragma unroll
        for (int r = 0; r < 4; ++r) {
            float mx = s[i][0][r];
            #pragma unroll
            for (int j = 1; j < 4; ++j) mx = fmaxf(mx, s[i][j][r]);
            #pragma unroll
            for (int d = 1; d < 16; d <<= 1) mx = fmaxf(mx, __shfl_xor(mx, d, 64));
            float sum = 0.f;
            #pragma unroll
            for (int j = 0; j < 4; ++j) {
                float p = __expf((s[i][j][r] - mx) * 0.125f);
                s[i][j][r] = p;
                sum += p;
            }
            #pragma unroll
            for (int d = 1; d < 16; d <<= 1) sum += __shfl_xor(sum, d, 64);
            rrec[i][r] = 1.f / sum;
        }
    }

    #pragma unroll
    for (int i = 0; i < 4; ++i)
        #pragma unroll
        for (int j = 0; j < 4; ++j)
            #pragma unroll
            for (int r = 0; r < 4; ++r) {
                const int row  = 16 * i + quad * 4 + r;
                const int col  = 16 * j + l16;
                const int slot = (col >> 3) ^ (row & 7);
                Kt[row * 64 + slot * 8 + (col & 7)] = (bf16)s[i][j][r];
            }
    __syncthreads();

    f32x4 o[4][4];
    #pragma unroll
    for (int i = 0; i < 4; ++i)
        #pragma unroll
        for (int j = 0; j < 4; ++j) o[i][j] = zero;

    #pragma unroll
    for (int ks = 0; ks < 2; ++ks) {
        bf16x8 pf[4], vf[4];
        #pragma unroll
        for (int i = 0; i < 4; ++i) {
            const int row  = 16 * i + l16;
            const int slot = (ks * 4 + quad) ^ (row & 7);
            pf[i] = *(const bf16x8*)(Kt + row * 64 + slot * 8);
        }
        #pragma unroll
        for (int j = 0; j < 4; ++j) {
            bf16x8 t;
            #pragma unroll
            for (int q = 0; q < 8; ++q)
                t[q] = Vt[(ks * 32 + quad * 8 + q) * 64 + 16 * j + l16];
            vf[j] = t;
        }
        #pragma unroll
        for (int i = 0; i < 4; ++i)
            #pragma unroll
            for (int j = 0; j < 4; ++j)
                o[i][j] = __builtin_amdgcn_mfma_f32_16x16x32_bf16(
                    pf[i], vf[j], o[i][j], 0, 0, 0);
    }

    #pragma unroll
    for (int i = 0; i < 4; ++i)
        #pragma unroll
        for (int j = 0; j < 4; ++j)
            #pragma unroll
            for (int r = 0; r < 4; ++r) {
                const size_t grow = rowbase + 16 * i + quad * 4 + r;
                const int col = h * 64 + 16 * j + l16;
                AOut[grow * 768 + col] = (bf16)(o[i][j][r] * rrec[i][r]);
            }
}

// ---------------------------------------------------------------------------
// Kernel 5: LN2 + fc1 (C->1) + exact gelu + fc2 (1->C). 1 wave per row.
// ---------------------------------------------------------------------------
__global__ __launch_bounds__(256)
void final_fused(const bf16* __restrict__ P, const float* __restrict__ g2,
                 const float* __restrict__ b2, const float* __restrict__ fc1w,
                 const float* __restrict__ fc1b, const float* __restrict__ fc2w,
                 const float* __restrict__ fc2b, float* __restrict__ out)
{
    const int row  = blockIdx.x * 4 + (threadIdx.x >> 6);
    const int lane = threadIdx.x & 63;
    const bf16* pr = P + (size_t)row * 768;
    float v[12];
    float sum = 0.f, ssq = 0.f;
    #pragma unroll
    for (int j = 0; j < 3; ++j) {
        bf16x4 c = *(const bf16x4*)(pr + j * 256 + lane * 4);
        #pragma unroll
        for (int q = 0; q < 4; ++q) {
            float f = (float)c[q];
            v[j * 4 + q] = f; sum += f; ssq += f * f;
        }
    }
    #pragma unroll
    for (int d = 1; d < 64; d <<= 1) {
        sum += __shfl_xor(sum, d, 64);
        ssq += __shfl_xor(ssq, d, 64);
    }
    const float mean = sum * (1.f / 768.f);
    const float rstd = rsqrtf(ssq * (1.f / 768.f) - mean * mean + 1e-5f);
    float part = 0.f;
    #pragma unroll
    for (int j = 0; j < 3; ++j) {
        const int c0 = j * 256 + lane * 4;
        f32x4 gg = *(const f32x4*)(g2 + c0);
        f32x4 bb = *(const f32x4*)(b2 + c0);
        f32x4 f1 = *(const f32x4*)(fc1w + c0);
        #pragma unroll
        for (int q = 0; q < 4; ++q) {
            float ln = (v[j * 4 + q] - mean) * rstd * gg[q] + bb[q];
            part += ln * f1[q];
        }
    }
    #pragma unroll
    for (int d = 1; d < 64; d <<= 1) part += __shfl_xor(part, d, 64);
    const float sv = part + fc1b[0];
    const float ge = 0.5f * sv * (1.f + erff(sv * 0.70710678118654752f));
    float* orow = out + (size_t)row * 768;
    #pragma unroll
    for (int j = 0; j < 3; ++j) {
        const int c0 = j * 256 + lane * 4;
        f32x4 f2  = *(const f32x4*)(fc2w + c0);
        f32x4 b2v = *(const f32x4*)(fc2b + c0);
        f32x4 ov;
        #pragma unroll
        for (int q = 0; q < 4; ++q)
            ov[q] = ge * f2[q] + b2v[q];
        *(f32x4*)(orow + c0) = ov;
    }
}

// ---------------------------------------------------------------------------
extern "C" void kernel_launch(void* const* d_in, const int* in_sizes, int n_in,
                              void* d_out, int out_size, void* d_ws, size_t ws_size,
                              hipStream_t stream)
{
    const float* x     = (const float*)d_in[0];
    const float* n1g   = (const float*)d_in[1];
    const float* n1b   = (const float*)d_in[2];
    const float* n2g   = (const float*)d_in[3];
    const float* n2b   = (const float*)d_in[4];
    const float* qkvw  = (const float*)d_in[5];
    const float* projw = (const float*)d_in[6];
    const float* projb = (const float*)d_in[7];
    const float* fc1w  = (const float*)d_in[8];
    const float* fc1b  = (const float*)d_in[9];
    const float* fc2w  = (const float*)d_in[10];
    const float* fc2b  = (const float*)d_in[11];
    float* out = (float*)d_out;

    const int total = in_sizes[0];          // B * 16384 * 768
    const int rows  = total / 768;          // 65536 token rows
    const int Smod  = total / 3;            // 2^24 for B=4
    const int Bw    = rows / 64;            // windows
    const int C     = 768;

    bf16* qkv     = (bf16*)d_ws;
    bf16* Ybuf    = qkv + (size_t)rows * 2304;
    bf16* qkvw_b  = Ybuf + (size_t)rows * 768;
    bf16* projw_b = qkvw_b + (size_t)3 * C * C;
    bf16* Pbuf    = qkv;
    // Gbuf lives in d_out scratch (33.5MB << out_size; final_fused fully
    // overwrites out afterwards, and is the only reader/writer of out).
    bf16* Gb      = (bf16*)d_out;

    const int nqkvw  = 3 * C * C;
    const int nprojw = C * C;
    f2b<<<(nqkvw / 4 + 255) / 256, 256, 0, stream>>>(qkvw, qkvw_b, nqkvw);
    f2b<<<(nprojw / 4 + 255) / 256, 256, 0, stream>>>(projw, projw_b, nprojw);

    ln1_win<<<rows / 4, 256, 0, stream>>>(x, n1g, n1b, Ybuf);

    gsum<<<(Smod / 8 + 255) / 256, 256, 0, stream>>>(Ybuf, Gb, Smod);

    const int nbm = rows / 128;             // 512 m-tiles
    gemm_bt<1, false, true><<<nbm * 9, 512, 0, stream>>>(
        nullptr, Ybuf, Gb, qkvw_b, nullptr, qkv, 768, 2304, Smod, 9);

    attn_win<<<Bw * 12, 64, 0, stream>>>(qkv, Ybuf);

    gemm_bt<0, true, false><<<nbm * 3, 512, 0, stream>>>(
        Ybuf, nullptr, nullptr, projw_b, projb, Pbuf, 768, 768, 0, 3);

    final_fused<<<rows / 4, 256, 0, stream>>>(Pbuf, n2g, n2b, fc1w, fc1b,
                                              fc2w, fc2b, out);
}

// Round 2
// 867.644 us; speedup vs baseline: 1.0476x; 1.0476x over previous
//
#include <hip/hip_runtime.h>
#include <hip/hip_bf16.h>
#include <stdint.h>
#include <stddef.h>

typedef __bf16 bf16;
typedef __bf16 bf16x4 __attribute__((ext_vector_type(4)));
typedef __bf16 bf16x8 __attribute__((ext_vector_type(8)));
typedef float  f32x4  __attribute__((ext_vector_type(4)));

__device__ __forceinline__ void async16(const void* src, void* dst) {
    __builtin_amdgcn_global_load_lds(
        (__attribute__((address_space(1))) void*)(void*)(src),
        (__attribute__((address_space(3))) void*)(dst),
        16, 0, 0);
}

#define MEMFENCE asm volatile("" ::: "memory")

__device__ __forceinline__ void barrier_f() {
    MEMFENCE;
    __builtin_amdgcn_s_barrier();
    MEMFENCE;
}

// ---------------------------------------------------------------------------
// Kernel 0: f32 -> bf16 weight conversion (n divisible by 4)
// ---------------------------------------------------------------------------
__global__ __launch_bounds__(256)
void f2b(const float* __restrict__ src, bf16* __restrict__ dst, int n)
{
    const int i = (blockIdx.x * 256 + threadIdx.x) * 4;
    if (i < n) {
        f32x4 c = *(const f32x4*)(src + i);
        bf16x4 o;
        #pragma unroll
        for (int q = 0; q < 4; ++q) o[q] = (bf16)c[q];
        *(bf16x4*)(dst + i) = o;
    }
}

// ---------------------------------------------------------------------------
// Kernel 1: LN over x rows (768, f32 in) + window permutation -> bf16 Y.
// ---------------------------------------------------------------------------
__global__ __launch_bounds__(256)
void ln1_win(const float* __restrict__ x, const float* __restrict__ g,
             const float* __restrict__ b, bf16* __restrict__ Y)
{
    const int row  = blockIdx.x * 4 + (threadIdx.x >> 6);
    const int lane = threadIdx.x & 63;
    const float* xr = x + (size_t)row * 768;
    float v[12];
    float sum = 0.f, ssq = 0.f;
    #pragma unroll
    for (int j = 0; j < 3; ++j) {
        f32x4 c = *(const f32x4*)(xr + j * 256 + lane * 4);
        #pragma unroll
        for (int q = 0; q < 4; ++q) {
            float f = c[q];
            v[j * 4 + q] = f; sum += f; ssq += f * f;
        }
    }
    #pragma unroll
    for (int d = 1; d < 64; d <<= 1) {
        sum += __shfl_xor(sum, d, 64);
        ssq += __shfl_xor(ssq, d, 64);
    }
    const float mean = sum * (1.f / 768.f);
    const float rstd = rsqrtf(ssq * (1.f / 768.f) - mean * mean + 1e-5f);
    const int bb = row >> 14;
    const int l  = row & 16383;
    const int hy = l >> 7, wx = l & 127;
    const int m  = ((bb * 256 + (hy >> 3) * 16 + (wx >> 3)) << 6)
                 + ((hy & 7) << 3) + (wx & 7);
    bf16* yr = Y + (size_t)m * 768;
    #pragma unroll
    for (int j = 0; j < 3; ++j) {
        const int c0 = j * 256 + lane * 4;
        f32x4 gg = *(const f32x4*)(g + c0);
        f32x4 bv = *(const f32x4*)(b + c0);
        bf16x4 ov;
        #pragma unroll
        for (int q = 0; q < 4; ++q)
            ov[q] = (bf16)((v[j * 4 + q] - mean) * rstd * gg[q] + bv[q]);
        *(bf16x4*)(yr + c0) = ov;
    }
}

// ---------------------------------------------------------------------------
// Kernel 1b: Gbuf[f] = Y[Smod+f] + Y[2*Smod+f]  (green+blue), f < Smod.
// ---------------------------------------------------------------------------
__global__ __launch_bounds__(256)
void gsum(const bf16* __restrict__ Y, bf16* __restrict__ G, int Smod)
{
    const int i = (blockIdx.x * 256 + threadIdx.x) * 8;
    if (i < Smod) {
        bf16x8 a = *(const bf16x8*)(Y + Smod + i);
        bf16x8 c = *(const bf16x8*)(Y + 2 * Smod + i);
        bf16x8 r;
        #pragma unroll
        for (int q = 0; q < 8; ++q) r[q] = (bf16)((float)a[q] + (float)c[q]);
        *(bf16x8*)(G + i) = r;
    }
}

// ---------------------------------------------------------------------------
// GEMM (8-phase, m201-style): C = A @ B^T (+bias).
// BM=256, BN=256, BK=64, 512 threads = 8 waves (2M x 4N), per-wave 128x64,
// acc[8][4] f32x4. LDS = 2 dbuf x { A[2ks][256][32], B[2ks][256][32] } bf16
// = 128 KB. Half-tile = one (matrix, ks) = 256x32 = 16KB = 2 loads/thread.
//
// Per K-tile kt (buf p=kt&1), 4 phases (ks,nh) = (0,0),(0,1),(1,0),(1,1):
//   phase: { ds_read frags | stage one half-tile | [vmcnt] | barrier |
//            lgkmcnt(0) | setprio(1) 16xMFMA setprio(0) | barrier }
// Stage mapping: P1 -> (kt+1).A-K1, P2 -> (kt+1).B-K1,
//                P3 -> (kt+2).A-K0, P4 -> (kt+2).B-K0.
// Counted waits: vmcnt(6) before closing barriers of P2 and P4 only
// (forces half-tiles staged >=4 phases ago complete); vmcnt(0) there for
// the last two K-tiles (stage skips would under-protect the counted wait).
// Region-free proof: each stage target's last reader finished >=1 closing
// barrier before the stage issue (A-K0 read only in P1, B-K0 in P1-P2,
// A-K1 in P3, B-K1 in P3-P4; fragments held in regs across nh phases).
//
// Swizzle: [256][32] halves, 16B granule: q_eff = q ^ ((row>>1)&3)
// -> 2-way bank aliasing on ds_read_b128 (free), linear gload_lds dest
// with pre-swizzled per-lane global source.
// XCD swizzle: bid&7 = XCD, contiguous m-chunk per XCD, nbase fastest.
// AMODE 1: A gathered from (nbase<768 ? Gbuf : Y) at (m*768+k) mod Smod.
// ---------------------------------------------------------------------------
template<int AMODE, bool BIAS>
__global__ __launch_bounds__(512, 2)
void gemm8p(const bf16* __restrict__ A, const bf16* __restrict__ Yg,
            const bf16* __restrict__ Gb, const bf16* __restrict__ Bm,
            const float* __restrict__ bias, bf16* __restrict__ Cm,
            int K, int ldc, int Smod, int nb_n)
{
    __shared__ bf16 lds[2 * 32768];            // 128 KB

    const int per    = gridDim.x >> 3;
    const int mchunk = per / nb_n;
    const int xcd    = blockIdx.x & 7;
    const int slot_b = blockIdx.x >> 3;
    const int mbase  = (xcd * mchunk + slot_b / nb_n) * 256;
    const int nbase  = (slot_b % nb_n) * 256;

    const int tid  = threadIdx.x;
    const int lane = tid & 63;
    const int w    = tid >> 6;
    const int quad = lane >> 4;
    const int l16  = lane & 15;
    const int wm   = (w >> 2) * 128;           // 2 M-waves
    const int wn   = (w & 3) * 64;             // 4 N-waves

    const bf16* Asrc = (AMODE == 1) ? ((nbase < 768) ? Gb : Yg) : A;
    const int nt = K >> 6;

    // stage one half-tile (X: 0=A, 1=B; ks) of K-tile kt into buf kt&1
    auto stage = [&](int kt, int X, int ks) {
        bf16* base = lds + (kt & 1) * 32768 + X * 16384 + ks * 8192;
        const int kb = kt * 64 + ks * 32;
        #pragma unroll
        for (int c = 0; c < 2; ++c) {
            const int idx = tid + c * 512;        // 0..1023 chunks of 8
            const int r   = idx >> 2;             // row 0..255
            const int q   = (idx & 3) ^ ((r >> 1) & 3);  // pre-swizzled src
            const bf16* s;
            if (X == 0) {
                if (AMODE == 1) {
                    int f = (mbase + r) * 768 + kb + q * 8;
                    if (f >= 2 * Smod) f -= 2 * Smod;
                    else if (f >= Smod) f -= Smod;
                    s = Asrc + f;
                } else {
                    s = Asrc + (size_t)(mbase + r) * K + kb + q * 8;
                }
            } else {
                s = Bm + (size_t)(nbase + r) * K + kb + q * 8;
            }
            async16(s, base + idx * 8);           // linear LDS dest
        }
    };

    auto readA = [&](bf16x8* af, int kt, int ks) {
        const bf16* base = lds + (kt & 1) * 32768 + ks * 8192;
        #pragma unroll
        for (int i = 0; i < 8; ++i) {
            const int r = wm + 16 * i + l16;
            const int q = quad ^ ((r >> 1) & 3);
            af[i] = *(const bf16x8*)(base + r * 32 + q * 8);
        }
    };
    auto readB = [&](bf16x8* bfr, int kt, int ks, int nh) {
        const bf16* base = lds + (kt & 1) * 32768 + 16384 + ks * 8192;
        #pragma unroll
        for (int j = 0; j < 2; ++j) {
            const int r = wn + nh * 32 + 16 * j + l16;
            const int q = quad ^ ((r >> 1) & 3);
            bfr[j] = *(const bf16x8*)(base + r * 32 + q * 8);
        }
    };

    const f32x4 zero = {0.f, 0.f, 0.f, 0.f};
    f32x4 acc[8][4];
    #pragma unroll
    for (int i = 0; i < 8; ++i)
        #pragma unroll
        for (int j = 0; j < 4; ++j) acc[i][j] = zero;

    auto mma16 = [&](const bf16x8* af, const bf16x8* bfr, int nh) {
        __builtin_amdgcn_s_setprio(1);
        #pragma unroll
        for (int i = 0; i < 8; ++i)
            #pragma unroll
            for (int jj = 0; jj < 2; ++jj)
                acc[i][nh * 2 + jj] = __builtin_amdgcn_mfma_f32_16x16x32_bf16(
                    af[i], bfr[jj], acc[i][nh * 2 + jj], 0, 0, 0);
        __builtin_amdgcn_s_setprio(0);
    };

    // ---- prologue: kt0 all 4 half-tiles + kt1 {A-K0, B-K0} ----
    stage(0, 0, 0); stage(0, 1, 0); stage(0, 0, 1); stage(0, 1, 1);
    if (nt > 1) { stage(1, 0, 0); stage(1, 1, 0); }
    asm volatile("s_waitcnt vmcnt(8)" ::: "memory");  // kt0.A-K0/B-K0 done
    barrier_f();

    bf16x8 af[8], bfr[2];
    for (int kt = 0; kt < nt; ++kt) {
        // ---- P1: (ks0, nh0) ----
        readA(af, kt, 0);
        readB(bfr, kt, 0, 0);
        if (kt + 1 < nt) stage(kt + 1, 0, 1);
        barrier_f();
        asm volatile("s_waitcnt lgkmcnt(0)" ::: "memory");
        mma16(af, bfr, 0);
        barrier_f();

        // ---- P2: (ks0, nh1) ----
        readB(bfr, kt, 0, 1);
        if (kt + 1 < nt) stage(kt + 1, 1, 1);
        if (kt < nt - 2) asm volatile("s_waitcnt vmcnt(6)" ::: "memory");
        else             asm volatile("s_waitcnt vmcnt(0)" ::: "memory");
        barrier_f();
        asm volatile("s_waitcnt lgkmcnt(0)" ::: "memory");
        mma16(af, bfr, 1);
        barrier_f();

        // ---- P3: (ks1, nh0) ----
        readA(af, kt, 1);
        readB(bfr, kt, 1, 0);
        if (kt + 2 < nt) stage(kt + 2, 0, 0);
        barrier_f();
        asm volatile("s_waitcnt lgkmcnt(0)" ::: "memory");
        mma16(af, bfr, 0);
        barrier_f();

        // ---- P4: (ks1, nh1) ----
        readB(bfr, kt, 1, 1);
        if (kt + 2 < nt) stage(kt + 2, 1, 0);
        if (kt < nt - 2) asm volatile("s_waitcnt vmcnt(6)" ::: "memory");
        else             asm volatile("s_waitcnt vmcnt(0)" ::: "memory");
        barrier_f();
        asm volatile("s_waitcnt lgkmcnt(0)" ::: "memory");
        mma16(af, bfr, 1);
        barrier_f();
    }

    // epilogue: C/D layout col=lane&15, row=quad*4+reg
    #pragma unroll
    for (int i = 0; i < 8; ++i) {
        const int row0 = mbase + wm + 16 * i + quad * 4;
        #pragma unroll
        for (int j = 0; j < 4; ++j) {
            const int col = nbase + wn + 16 * j + l16;
            float bv = 0.f;
            if (BIAS) bv = bias[col];
            #pragma unroll
            for (int r = 0; r < 4; ++r)
                Cm[(size_t)(row0 + r) * ldc + col] = (bf16)(acc[i][j][r] + bv);
        }
    }
}

// ---------------------------------------------------------------------------
// Kernel 3: windowed attention, one wave per (window, head). 64x64 tiles.
// ---------------------------------------------------------------------------
__global__ __launch_bounds__(64)
void attn_win(const bf16* __restrict__ QKV, bf16* __restrict__ AOut)
{
    const int blk  = blockIdx.x;
    const int bw   = blk / 12;
    const int h    = blk % 12;
    const int lane = threadIdx.x;
    const int quad = lane >> 4;
    const int l16  = lane & 15;

    __shared__ bf16 Kt[64 * 64];
    __shared__ bf16 Vt[64 * 64];

    const size_t rowbase = (size_t)bw * 64;

    {
        const int rsub = lane >> 3;
        const int slot = lane & 7;
        #pragma unroll
        for (int t = 0; t < 8; ++t) {
            const int row = 8 * t + rsub;
            const int kcK = slot ^ (row & 7);
            async16(QKV + (rowbase + row) * 2304 + 768 + h * 64 + kcK * 8,
                    Kt + (8 * t) * 64);
            async16(QKV + (rowbase + row) * 2304 + 1536 + h * 64 + slot * 8,
                    Vt + (8 * t) * 64);
        }
    }

    bf16x8 qf[4][2];
    #pragma unroll
    for (int i = 0; i < 4; ++i)
        #pragma unroll
        for (int ks = 0; ks < 2; ++ks)
            qf[i][ks] = *(const bf16x8*)(QKV + (rowbase + 16 * i + l16) * 2304
                                         + h * 64 + ks * 32 + quad * 8);
    __syncthreads();

    const f32x4 zero = {0.f, 0.f, 0.f, 0.f};
    f32x4 s[4][4];
    #pragma unroll
    for (int i = 0; i < 4; ++i)
        #pragma unroll
        for (int j = 0; j < 4; ++j) s[i][j] = zero;

    #pragma unroll
    for (int ks = 0; ks < 2; ++ks) {
        bf16x8 kf[4];
        #pragma unroll
        for (int j = 0; j < 4; ++j) {
            const int row  = 16 * j + l16;
            const int slot = (ks * 4 + quad) ^ (row & 7);
            kf[j] = *(const bf16x8*)(Kt + row * 64 + slot * 8);
        }
        #pragma unroll
        for (int i = 0; i < 4; ++i)
            #pragma unroll
            for (int j = 0; j < 4; ++j)
                s[i][j] = __builtin_amdgcn_mfma_f32_16x16x32_bf16(
                    qf[i][ks], kf[j], s[i][j], 0, 0, 0);
    }

    float rrec[4][4];
    #pragma unroll
    for (int i = 0; i < 4; ++i) {
        #pragma unroll
        for (int r = 0; r < 4; ++r) {
            float mx = s[i][0][r];
            #pragma unroll
            for (int j = 1; j < 4; ++j) mx = fmaxf(mx, s[i][j][r]);
            #pragma unroll
            for (int d = 1; d < 16; d <<= 1) mx = fmaxf(mx, __shfl_xor(mx, d, 64));
            float sum = 0.f;
            #pragma unroll
            for (int j = 0; j < 4; ++j) {
                float p = __expf((s[i][j][r] - mx) * 0.125f);
                s[i][j][r] = p;
                sum += p;
            }
            #pragma unroll
            for (int d = 1; d < 16; d <<= 1) sum += __shfl_xor(sum, d, 64);
            rrec[i][r] = 1.f / sum;
        }
    }

    #pragma unroll
    for (int i = 0; i < 4; ++i)
        #pragma unroll
        for (int j = 0; j < 4; ++j)
            #pragma unroll
            for (int r = 0; r < 4; ++r) {
                const int row  = 16 * i + quad * 4 + r;
                const int col  = 16 * j + l16;
                const int slot = (col >> 3) ^ (row & 7);
                Kt[row * 64 + slot * 8 + (col & 7)] = (bf16)s[i][j][r];
            }
    __syncthreads();

    f32x4 o[4][4];
    #pragma unroll
    for (int i = 0; i < 4; ++i)
        #pragma unroll
        for (int j = 0; j < 4; ++j) o[i][j] = zero;

    #pragma unroll
    for (int ks = 0; ks < 2; ++ks) {
        bf16x8 pf[4], vf[4];
        #pragma unroll
        for (int i = 0; i < 4; ++i) {
            const int row  = 16 * i + l16;
            const int slot = (ks * 4 + quad) ^ (row & 7);
            pf[i] = *(const bf16x8*)(Kt + row * 64 + slot * 8);
        }
        #pragma unroll
        for (int j = 0; j < 4; ++j) {
            bf16x8 t;
            #pragma unroll
            for (int q = 0; q < 8; ++q)
                t[q] = Vt[(ks * 32 + quad * 8 + q) * 64 + 16 * j + l16];
            vf[j] = t;
        }
        #pragma unroll
        for (int i = 0; i < 4; ++i)
            #pragma unroll
            for (int j = 0; j < 4; ++j)
                o[i][j] = __builtin_amdgcn_mfma_f32_16x16x32_bf16(
                    pf[i], vf[j], o[i][j], 0, 0, 0);
    }

    #pragma unroll
    for (int i = 0; i < 4; ++i)
        #pragma unroll
        for (int j = 0; j < 4; ++j)
            #pragma unroll
            for (int r = 0; r < 4; ++r) {
                const size_t grow = rowbase + 16 * i + quad * 4 + r;
                const int col = h * 64 + 16 * j + l16;
                AOut[grow * 768 + col] = (bf16)(o[i][j][r] * rrec[i][r]);
            }
}

// ---------------------------------------------------------------------------
// Kernel 5: LN2 + fc1 (C->1) + exact gelu + fc2 (1->C). 1 wave per row.
// ---------------------------------------------------------------------------
__global__ __launch_bounds__(256)
void final_fused(const bf16* __restrict__ P, const float* __restrict__ g2,
                 const float* __restrict__ b2, const float* __restrict__ fc1w,
                 const float* __restrict__ fc1b, const float* __restrict__ fc2w,
                 const float* __restrict__ fc2b, float* __restrict__ out)
{
    const int row  = blockIdx.x * 4 + (threadIdx.x >> 6);
    const int lane = threadIdx.x & 63;
    const bf16* pr = P + (size_t)row * 768;
    float v[12];
    float sum = 0.f, ssq = 0.f;
    #pragma unroll
    for (int j = 0; j < 3; ++j) {
        bf16x4 c = *(const bf16x4*)(pr + j * 256 + lane * 4);
        #pragma unroll
        for (int q = 0; q < 4; ++q) {
            float f = (float)c[q];
            v[j * 4 + q] = f; sum += f; ssq += f * f;
        }
    }
    #pragma unroll
    for (int d = 1; d < 64; d <<= 1) {
        sum += __shfl_xor(sum, d, 64);
        ssq += __shfl_xor(ssq, d, 64);
    }
    const float mean = sum * (1.f / 768.f);
    const float rstd = rsqrtf(ssq * (1.f / 768.f) - mean * mean + 1e-5f);
    float part = 0.f;
    #pragma unroll
    for (int j = 0; j < 3; ++j) {
        const int c0 = j * 256 + lane * 4;
        f32x4 gg = *(const f32x4*)(g2 + c0);
        f32x4 bb = *(const f32x4*)(b2 + c0);
        f32x4 f1 = *(const f32x4*)(fc1w + c0);
        #pragma unroll
        for (int q = 0; q < 4; ++q) {
            float ln = (v[j * 4 + q] - mean) * rstd * gg[q] + bb[q];
            part += ln * f1[q];
        }
    }
    #pragma unroll
    for (int d = 1; d < 64; d <<= 1) part += __shfl_xor(part, d, 64);
    const float sv = part + fc1b[0];
    const float ge = 0.5f * sv * (1.f + erff(sv * 0.70710678118654752f));
    float* orow = out + (size_t)row * 768;
    #pragma unroll
    for (int j = 0; j < 3; ++j) {
        const int c0 = j * 256 + lane * 4;
        f32x4 f2  = *(const f32x4*)(fc2w + c0);
        f32x4 b2v = *(const f32x4*)(fc2b + c0);
        f32x4 ov;
        #pragma unroll
        for (int q = 0; q < 4; ++q)
            ov[q] = ge * f2[q] + b2v[q];
        *(f32x4*)(orow + c0) = ov;
    }
}

// ---------------------------------------------------------------------------
extern "C" void kernel_launch(void* const* d_in, const int* in_sizes, int n_in,
                              void* d_out, int out_size, void* d_ws, size_t ws_size,
                              hipStream_t stream)
{
    const float* x     = (const float*)d_in[0];
    const float* n1g   = (const float*)d_in[1];
    const float* n1b   = (const float*)d_in[2];
    const float* n2g   = (const float*)d_in[3];
    const float* n2b   = (const float*)d_in[4];
    const float* qkvw  = (const float*)d_in[5];
    const float* projw = (const float*)d_in[6];
    const float* projb = (const float*)d_in[7];
    const float* fc1w  = (const float*)d_in[8];
    const float* fc1b  = (const float*)d_in[9];
    const float* fc2w  = (const float*)d_in[10];
    const float* fc2b  = (const float*)d_in[11];
    float* out = (float*)d_out;

    const int total = in_sizes[0];          // B * 16384 * 768
    const int rows  = total / 768;          // 65536 token rows
    const int Smod  = total / 3;            // 2^24 for B=4
    const int Bw    = rows / 64;            // windows
    const int C     = 768;

    bf16* qkv     = (bf16*)d_ws;
    bf16* Ybuf    = qkv + (size_t)rows * 2304;
    bf16* qkvw_b  = Ybuf + (size_t)rows * 768;
    bf16* projw_b = qkvw_b + (size_t)3 * C * C;
    bf16* Pbuf    = qkv;
    // Gbuf lives in d_out scratch (33.5MB << out_size; final_fused fully
    // overwrites out afterwards).
    bf16* Gb      = (bf16*)d_out;

    const int nqkvw  = 3 * C * C;
    const int nprojw = C * C;
    f2b<<<(nqkvw / 4 + 255) / 256, 256, 0, stream>>>(qkvw, qkvw_b, nqkvw);
    f2b<<<(nprojw / 4 + 255) / 256, 256, 0, stream>>>(projw, projw_b, nprojw);

    ln1_win<<<rows / 4, 256, 0, stream>>>(x, n1g, n1b, Ybuf);

    gsum<<<(Smod / 8 + 255) / 256, 256, 0, stream>>>(Ybuf, Gb, Smod);

    const int nbm = rows / 256;             // 256 m-tiles
    gemm8p<1, false><<<nbm * 9, 512, 0, stream>>>(
        nullptr, Ybuf, Gb, qkvw_b, nullptr, qkv, 768, 2304, Smod, 9);

    attn_win<<<Bw * 12, 64, 0, stream>>>(qkv, Ybuf);

    gemm8p<0, true><<<nbm * 3, 512, 0, stream>>>(
        Ybuf, nullptr, nullptr, projw_b, projb, Pbuf, 768, 768, 0, 3);

    final_fused<<<rows / 4, 256, 0, stream>>>(Pbuf, n2g, n2b, fc1w, fc1b,
                                              fc2w, fc2b, out);
}

// Round 3
// 858.613 us; speedup vs baseline: 1.0587x; 1.0105x over previous
//
#include <hip/hip_runtime.h>
#include <hip/hip_bf16.h>
#include <stdint.h>
#include <stddef.h>

typedef __bf16 bf16;
typedef __bf16 bf16x4 __attribute__((ext_vector_type(4)));
typedef __bf16 bf16x8 __attribute__((ext_vector_type(8)));
typedef float  f32x4  __attribute__((ext_vector_type(4)));

__device__ __forceinline__ void async16(const void* src, void* dst) {
    __builtin_amdgcn_global_load_lds(
        (__attribute__((address_space(1))) void*)(void*)(src),
        (__attribute__((address_space(3))) void*)(dst),
        16, 0, 0);
}

#define MEMFENCE asm volatile("" ::: "memory")

__device__ __forceinline__ void barrier_f() {
    MEMFENCE;
    __builtin_amdgcn_s_barrier();
    MEMFENCE;
}

// ---------------------------------------------------------------------------
// Kernel 0: f32 -> bf16 weight conversion (n divisible by 4)
// ---------------------------------------------------------------------------
__global__ __launch_bounds__(256)
void f2b(const float* __restrict__ src, bf16* __restrict__ dst, int n)
{
    const int i = (blockIdx.x * 256 + threadIdx.x) * 4;
    if (i < n) {
        f32x4 c = *(const f32x4*)(src + i);
        bf16x4 o;
        #pragma unroll
        for (int q = 0; q < 4; ++q) o[q] = (bf16)c[q];
        *(bf16x4*)(dst + i) = o;
    }
}

// ---------------------------------------------------------------------------
// Kernel 1: LN over x rows (768, f32 in) + window permutation -> bf16 Y.
// ---------------------------------------------------------------------------
__global__ __launch_bounds__(256)
void ln1_win(const float* __restrict__ x, const float* __restrict__ g,
             const float* __restrict__ b, bf16* __restrict__ Y)
{
    const int row  = blockIdx.x * 4 + (threadIdx.x >> 6);
    const int lane = threadIdx.x & 63;
    const float* xr = x + (size_t)row * 768;
    float v[12];
    float sum = 0.f, ssq = 0.f;
    #pragma unroll
    for (int j = 0; j < 3; ++j) {
        f32x4 c = *(const f32x4*)(xr + j * 256 + lane * 4);
        #pragma unroll
        for (int q = 0; q < 4; ++q) {
            float f = c[q];
            v[j * 4 + q] = f; sum += f; ssq += f * f;
        }
    }
    #pragma unroll
    for (int d = 1; d < 64; d <<= 1) {
        sum += __shfl_xor(sum, d, 64);
        ssq += __shfl_xor(ssq, d, 64);
    }
    const float mean = sum * (1.f / 768.f);
    const float rstd = rsqrtf(ssq * (1.f / 768.f) - mean * mean + 1e-5f);
    const int bb = row >> 14;
    const int l  = row & 16383;
    const int hy = l >> 7, wx = l & 127;
    const int m  = ((bb * 256 + (hy >> 3) * 16 + (wx >> 3)) << 6)
                 + ((hy & 7) << 3) + (wx & 7);
    bf16* yr = Y + (size_t)m * 768;
    #pragma unroll
    for (int j = 0; j < 3; ++j) {
        const int c0 = j * 256 + lane * 4;
        f32x4 gg = *(const f32x4*)(g + c0);
        f32x4 bv = *(const f32x4*)(b + c0);
        bf16x4 ov;
        #pragma unroll
        for (int q = 0; q < 4; ++q)
            ov[q] = (bf16)((v[j * 4 + q] - mean) * rstd * gg[q] + bv[q]);
        *(bf16x4*)(yr + c0) = ov;
    }
}

// ---------------------------------------------------------------------------
// Kernel 1b: Gbuf[f] = Y[Smod+f] + Y[2*Smod+f]  (green+blue), f < Smod.
// ---------------------------------------------------------------------------
__global__ __launch_bounds__(256)
void gsum(const bf16* __restrict__ Y, bf16* __restrict__ G, int Smod)
{
    const int i = (blockIdx.x * 256 + threadIdx.x) * 8;
    if (i < Smod) {
        bf16x8 a = *(const bf16x8*)(Y + Smod + i);
        bf16x8 c = *(const bf16x8*)(Y + 2 * Smod + i);
        bf16x8 r;
        #pragma unroll
        for (int q = 0; q < 8; ++q) r[q] = (bf16)((float)a[q] + (float)c[q]);
        *(bf16x8*)(G + i) = r;
    }
}

// ---------------------------------------------------------------------------
// GEMM, single-barrier overlapped 4-phase schedule.  C = A @ B^T (+bias).
// BM=256, BN=256, BK=64, 512 threads = 8 waves (2M x 4N), per-wave 128x64.
// LDS = 2 dbuf x { A[2ks][256][32] | B[2ks][256][32] } = 128 KB.
//
// Phase = { s_barrier ; 16 MFMA (frags read LAST phase) ; issue ds_reads
//           for NEXT phase ; [stage 4 gload_lds] ; [counted vmcnt] }.
// MFMA issue fills the matrix pipe, then ds_read drain + staging VMEM issue
// hide under the in-flight MFMA window; next phase's MFMA stalls only on
// pipe-full -> pipe continuously fed across barriers (T3/T4 done properly).
//
// Frags: A single-buffered (overwritten after consuming MFMAs issue, same
// wave program order); B double-buffered b0(nh0)/b1(nh1).
// Staging: P1 stages (kt+1).K1, P3 stages (kt+2).K0 (4 loads each).
// FIFO ledger (per wave, groups of 4): steady in-flight = 3 groups at the
// vmcnt points -> vmcnt(8) retires the group needed 1 phase later:
//   end-P1(kt): retire (kt).K1  (read at P2)
//   end-P3(kt): retire (kt+1).K0 (read at P4)
// Tail: P1 vm = kt+1<nt ? 8 : 0 ; P3 vm = kt+2<nt ? 8 : (kt+1<nt ? 4 : 0).
// WAR safety: every staged region's last reader completed >=2 barriers
// before the overwrite (verified per-region).
//
// Swizzle (same as verified round-2): [256][32] halves, chunk c of row r
// holds source col c ^ ((r>>1)&3)  -> 2-way bank aliasing (free), linear
// gload_lds dest, pre-swizzled per-lane global source.
// XCD swizzle: bid&7 = XCD, contiguous m-chunk per XCD, nbase fastest.
// AMODE 1: A gathered from (nbase<768 ? Gbuf : Y) at (m*768+k) mod Smod.
// ---------------------------------------------------------------------------
template<int AMODE, bool BIAS>
__global__ __launch_bounds__(512, 2)
void gemm8p(const bf16* __restrict__ A, const bf16* __restrict__ Yg,
            const bf16* __restrict__ Gb, const bf16* __restrict__ Bm,
            const float* __restrict__ bias, bf16* __restrict__ Cm,
            int K, int ldc, int Smod, int nb_n)
{
    __shared__ bf16 lds[2 * 32768];            // 128 KB

    const int per    = gridDim.x >> 3;
    const int mchunk = per / nb_n;
    const int xcd    = blockIdx.x & 7;
    const int slot_b = blockIdx.x >> 3;
    const int mbase  = (xcd * mchunk + slot_b / nb_n) * 256;
    const int nbase  = (slot_b % nb_n) * 256;

    const int tid  = threadIdx.x;
    const int lane = tid & 63;
    const int w    = tid >> 6;
    const int quad = lane >> 4;
    const int l16  = lane & 15;
    const int wm   = (w >> 2) * 128;           // 2 M-waves
    const int wn   = (w & 3) * 64;             // 4 N-waves

    const bf16* Asrc = (AMODE == 1) ? ((nbase < 768) ? Gb : Yg) : A;
    const int nt = K >> 6;

    // ---- per-thread staging constants (computed once) ----
    const int r0 = tid >> 2, r1 = r0 + 128;
    const int q0 = (tid & 3) ^ ((r0 >> 1) & 3);
    const int q1 = (tid & 3) ^ ((r1 >> 1) & 3);
    const int lo0 = tid * 8, lo1 = tid * 8 + 4096;   // LDS elem offsets

    int f0A0 = 0, f0A1 = 0;
    const bf16 *aP0 = nullptr, *aP1 = nullptr;
    if (AMODE == 1) {
        f0A0 = (mbase + r0) * 768 + q0 * 8;
        if (f0A0 >= 2 * Smod) f0A0 -= 2 * Smod;
        else if (f0A0 >= Smod) f0A0 -= Smod;
        f0A1 = (mbase + r1) * 768 + q1 * 8;
        if (f0A1 >= 2 * Smod) f0A1 -= 2 * Smod;
        else if (f0A1 >= Smod) f0A1 -= Smod;
    } else {
        aP0 = A + (size_t)(mbase + r0) * K + q0 * 8;
        aP1 = A + (size_t)(mbase + r1) * K + q1 * 8;
    }
    const bf16* bP0 = Bm + (size_t)(nbase + r0) * K + q0 * 8;
    const bf16* bP1 = Bm + (size_t)(nbase + r1) * K + q1 * 8;

    // stage one full K-half (A 256x32 + B 256x32, 4 loads) of tile kt
    auto stageK = [&](int kt, int ks) {
        const int kb = kt * 64 + ks * 32;
        bf16* dst = lds + (kt & 1) * 32768 + ks * 8192;
        const bf16 *s0, *s1;
        if (AMODE == 1) {
            int f = f0A0 + kb; if (f >= Smod) f -= Smod;
            int g = f0A1 + kb; if (g >= Smod) g -= Smod;
            s0 = Asrc + f; s1 = Asrc + g;
        } else {
            s0 = aP0 + kb; s1 = aP1 + kb;
        }
        async16(s0, dst + lo0);
        async16(s1, dst + lo1);
        async16(bP0 + kb, dst + 16384 + lo0);
        async16(bP1 + kb, dst + 16384 + lo1);
    };

    // ---- per-thread LDS read offsets (elements) ----
    int aoff[8], boff[2][2];
    #pragma unroll
    for (int i = 0; i < 8; ++i) {
        const int r = wm + 16 * i + l16;
        aoff[i] = r * 32 + (quad ^ ((r >> 1) & 3)) * 8;
    }
    #pragma unroll
    for (int nh = 0; nh < 2; ++nh)
        #pragma unroll
        for (int j = 0; j < 2; ++j) {
            const int r = wn + nh * 32 + 16 * j + l16;
            boff[nh][j] = r * 32 + (quad ^ ((r >> 1) & 3)) * 8;
        }

    bf16x8 af[8], b0[2], b1[2];
    auto readA = [&](int p, int ks) {
        const bf16* base = lds + p + ks * 8192;
        #pragma unroll
        for (int i = 0; i < 8; ++i) af[i] = *(const bf16x8*)(base + aoff[i]);
    };
    auto readB0 = [&](int p, int ks, int nh) {
        const bf16* base = lds + p + 16384 + ks * 8192;
        #pragma unroll
        for (int j = 0; j < 2; ++j) b0[j] = *(const bf16x8*)(base + boff[nh][j]);
    };
    auto readB1 = [&](int p, int ks, int nh) {
        const bf16* base = lds + p + 16384 + ks * 8192;
        #pragma unroll
        for (int j = 0; j < 2; ++j) b1[j] = *(const bf16x8*)(base + boff[nh][j]);
    };

    const f32x4 zero = {0.f, 0.f, 0.f, 0.f};
    f32x4 acc[8][4];
    #pragma unroll
    for (int i = 0; i < 8; ++i)
        #pragma unroll
        for (int j = 0; j < 4; ++j) acc[i][j] = zero;

    auto mma16 = [&](const bf16x8* bb, int ch) {
        __builtin_amdgcn_s_setprio(1);
        #pragma unroll
        for (int i = 0; i < 8; ++i)
            #pragma unroll
            for (int jj = 0; jj < 2; ++jj)
                acc[i][ch * 2 + jj] = __builtin_amdgcn_mfma_f32_16x16x32_bf16(
                    af[i], bb[jj], acc[i][ch * 2 + jj], 0, 0, 0);
        __builtin_amdgcn_s_setprio(0);
    };

    // ---- prologue: stage (0).K0, (0).K1, (1).K0; wait (0).K0; preload P1 ----
    stageK(0, 0); stageK(0, 1);
    if (nt > 1) {
        stageK(1, 0);
        asm volatile("s_waitcnt vmcnt(8)" ::: "memory");
    } else {
        asm volatile("s_waitcnt vmcnt(4)" ::: "memory");
    }
    barrier_f();
    readA(0, 0);
    readB0(0, 0, 0);

    for (int kt = 0; kt < nt; ++kt) {
        const int p = (kt & 1) * 32768;

        // ---- P1: MFMA(ks0, nh0) ----
        barrier_f();
        mma16(b0, 0);
        readB1(p, 0, 1);                       // for P2
        if (kt + 1 < nt) {
            stageK(kt + 1, 1);
            asm volatile("s_waitcnt vmcnt(8)" ::: "memory");
        } else {
            asm volatile("s_waitcnt vmcnt(0)" ::: "memory");
        }

        // ---- P2: MFMA(ks0, nh1) ----
        barrier_f();
        mma16(b1, 1);
        readA(p, 1);                           // for P3 (overwrites af)
        readB0(p, 1, 0);                       // for P3

        // ---- P3: MFMA(ks1, nh0) ----
        barrier_f();
        mma16(b0, 0);
        readB1(p, 1, 1);                       // for P4
        if (kt + 2 < nt) {
            stageK(kt + 2, 0);
            asm volatile("s_waitcnt vmcnt(8)" ::: "memory");
        } else if (kt + 1 < nt) {
            asm volatile("s_waitcnt vmcnt(4)" ::: "memory");
        } else {
            asm volatile("s_waitcnt vmcnt(0)" ::: "memory");
        }

        // ---- P4: MFMA(ks1, nh1) ----
        barrier_f();
        mma16(b1, 1);
        if (kt + 1 < nt) {
            const int pn = ((kt + 1) & 1) * 32768;
            readA(pn, 0);                      // for P1(kt+1)
            readB0(pn, 0, 0);
        }
    }

    // epilogue: C/D layout col=lane&15, row=quad*4+reg
    #pragma unroll
    for (int i = 0; i < 8; ++i) {
        const int row0 = mbase + wm + 16 * i + quad * 4;
        #pragma unroll
        for (int j = 0; j < 4; ++j) {
            const int col = nbase + wn + 16 * j + l16;
            float bv = 0.f;
            if (BIAS) bv = bias[col];
            #pragma unroll
            for (int r = 0; r < 4; ++r)
                Cm[(size_t)(row0 + r) * ldc + col] = (bf16)(acc[i][j][r] + bv);
        }
    }
}

// ---------------------------------------------------------------------------
// Kernel 3: windowed attention, one wave per (window, head). 64x64 tiles.
// ---------------------------------------------------------------------------
__global__ __launch_bounds__(64)
void attn_win(const bf16* __restrict__ QKV, bf16* __restrict__ AOut)
{
    const int blk  = blockIdx.x;
    const int bw   = blk / 12;
    const int h    = blk % 12;
    const int lane = threadIdx.x;
    const int quad = lane >> 4;
    const int l16  = lane & 15;

    __shared__ bf16 Kt[64 * 64];
    __shared__ bf16 Vt[64 * 64];

    const size_t rowbase = (size_t)bw * 64;

    {
        const int rsub = lane >> 3;
        const int slot = lane & 7;
        #pragma unroll
        for (int t = 0; t < 8; ++t) {
            const int row = 8 * t + rsub;
            const int kcK = slot ^ (row & 7);
            async16(QKV + (rowbase + row) * 2304 + 768 + h * 64 + kcK * 8,
                    Kt + (8 * t) * 64);
            async16(QKV + (rowbase + row) * 2304 + 1536 + h * 64 + slot * 8,
                    Vt + (8 * t) * 64);
        }
    }

    bf16x8 qf[4][2];
    #pragma unroll
    for (int i = 0; i < 4; ++i)
        #pragma unroll
        for (int ks = 0; ks < 2; ++ks)
            qf[i][ks] = *(const bf16x8*)(QKV + (rowbase + 16 * i + l16) * 2304
                                         + h * 64 + ks * 32 + quad * 8);
    __syncthreads();

    const f32x4 zero = {0.f, 0.f, 0.f, 0.f};
    f32x4 s[4][4];
    #pragma unroll
    for (int i = 0; i < 4; ++i)
        #pragma unroll
        for (int j = 0; j < 4; ++j) s[i][j] = zero;

    #pragma unroll
    for (int ks = 0; ks < 2; ++ks) {
        bf16x8 kf[4];
        #pragma unroll
        for (int j = 0; j < 4; ++j) {
            const int row  = 16 * j + l16;
            const int slot = (ks * 4 + quad) ^ (row & 7);
            kf[j] = *(const bf16x8*)(Kt + row * 64 + slot * 8);
        }
        #pragma unroll
        for (int i = 0; i < 4; ++i)
            #pragma unroll
            for (int j = 0; j < 4; ++j)
                s[i][j] = __builtin_amdgcn_mfma_f32_16x16x32_bf16(
                    qf[i][ks], kf[j], s[i][j], 0, 0, 0);
    }

    float rrec[4][4];
    #pragma unroll
    for (int i = 0; i < 4; ++i) {
        #pragma unroll
        for (int r = 0; r < 4; ++r) {
            float mx = s[i][0][r];
            #pragma unroll
            for (int j = 1; j < 4; ++j) mx = fmaxf(mx, s[i][j][r]);
            #pragma unroll
            for (int d = 1; d < 16; d <<= 1) mx = fmaxf(mx, __shfl_xor(mx, d, 64));
            float sum = 0.f;
            #pragma unroll
            for (int j = 0; j < 4; ++j) {
                float p = __expf((s[i][j][r] - mx) * 0.125f);
                s[i][j][r] = p;
                sum += p;
            }
            #pragma unroll
            for (int d = 1; d < 16; d <<= 1) sum += __shfl_xor(sum, d, 64);
            rrec[i][r] = 1.f / sum;
        }
    }

    #pragma unroll
    for (int i = 0; i < 4; ++i)
        #pragma unroll
        for (int j = 0; j < 4; ++j)
            #pragma unroll
            for (int r = 0; r < 4; ++r) {
                const int row  = 16 * i + quad * 4 + r;
                const int col  = 16 * j + l16;
                const int slot = (col >> 3) ^ (row & 7);
                Kt[row * 64 + slot * 8 + (col & 7)] = (bf16)s[i][j][r];
            }
    __syncthreads();

    f32x4 o[4][4];
    #pragma unroll
    for (int i = 0; i < 4; ++i)
        #pragma unroll
        for (int j = 0; j < 4; ++j) o[i][j] = zero;

    #pragma unroll
    for (int ks = 0; ks < 2; ++ks) {
        bf16x8 pf[4], vf[4];
        #pragma unroll
        for (int i = 0; i < 4; ++i) {
            const int row  = 16 * i + l16;
            const int slot = (ks * 4 + quad) ^ (row & 7);
            pf[i] = *(const bf16x8*)(Kt + row * 64 + slot * 8);
        }
        #pragma unroll
        for (int j = 0; j < 4; ++j) {
            bf16x8 t;
            #pragma unroll
            for (int q = 0; q < 8; ++q)
                t[q] = Vt[(ks * 32 + quad * 8 + q) * 64 + 16 * j + l16];
            vf[j] = t;
        }
        #pragma unroll
        for (int i = 0; i < 4; ++i)
            #pragma unroll
            for (int j = 0; j < 4; ++j)
                o[i][j] = __builtin_amdgcn_mfma_f32_16x16x32_bf16(
                    pf[i], vf[j], o[i][j], 0, 0, 0);
    }

    #pragma unroll
    for (int i = 0; i < 4; ++i)
        #pragma unroll
        for (int j = 0; j < 4; ++j)
            #pragma unroll
            for (int r = 0; r < 4; ++r) {
                const size_t grow = rowbase + 16 * i + quad * 4 + r;
                const int col = h * 64 + 16 * j + l16;
                AOut[grow * 768 + col] = (bf16)(o[i][j][r] * rrec[i][r]);
            }
}

// ---------------------------------------------------------------------------
// Kernel 5: LN2 + fc1 (C->1) + exact gelu + fc2 (1->C). 1 wave per row.
// ---------------------------------------------------------------------------
__global__ __launch_bounds__(256)
void final_fused(const bf16* __restrict__ P, const float* __restrict__ g2,
                 const float* __restrict__ b2, const float* __restrict__ fc1w,
                 const float* __restrict__ fc1b, const float* __restrict__ fc2w,
                 const float* __restrict__ fc2b, float* __restrict__ out)
{
    const int row  = blockIdx.x * 4 + (threadIdx.x >> 6);
    const int lane = threadIdx.x & 63;
    const bf16* pr = P + (size_t)row * 768;
    float v[12];
    float sum = 0.f, ssq = 0.f;
    #pragma unroll
    for (int j = 0; j < 3; ++j) {
        bf16x4 c = *(const bf16x4*)(pr + j * 256 + lane * 4);
        #pragma unroll
        for (int q = 0; q < 4; ++q) {
            float f = (float)c[q];
            v[j * 4 + q] = f; sum += f; ssq += f * f;
        }
    }
    #pragma unroll
    for (int d = 1; d < 64; d <<= 1) {
        sum += __shfl_xor(sum, d, 64);
        ssq += __shfl_xor(ssq, d, 64);
    }
    const float mean = sum * (1.f / 768.f);
    const float rstd = rsqrtf(ssq * (1.f / 768.f) - mean * mean + 1e-5f);
    float part = 0.f;
    #pragma unroll
    for (int j = 0; j < 3; ++j) {
        const int c0 = j * 256 + lane * 4;
        f32x4 gg = *(const f32x4*)(g2 + c0);
        f32x4 bb = *(const f32x4*)(b2 + c0);
        f32x4 f1 = *(const f32x4*)(fc1w + c0);
        #pragma unroll
        for (int q = 0; q < 4; ++q) {
            float ln = (v[j * 4 + q] - mean) * rstd * gg[q] + bb[q];
            part += ln * f1[q];
        }
    }
    #pragma unroll
    for (int d = 1; d < 64; d <<= 1) part += __shfl_xor(part, d, 64);
    const float sv = part + fc1b[0];
    const float ge = 0.5f * sv * (1.f + erff(sv * 0.70710678118654752f));
    float* orow = out + (size_t)row * 768;
    #pragma unroll
    for (int j = 0; j < 3; ++j) {
        const int c0 = j * 256 + lane * 4;
        f32x4 f2  = *(const f32x4*)(fc2w + c0);
        f32x4 b2v = *(const f32x4*)(fc2b + c0);
        f32x4 ov;
        #pragma unroll
        for (int q = 0; q < 4; ++q)
            ov[q] = ge * f2[q] + b2v[q];
        *(f32x4*)(orow + c0) = ov;
    }
}

// ---------------------------------------------------------------------------
extern "C" void kernel_launch(void* const* d_in, const int* in_sizes, int n_in,
                              void* d_out, int out_size, void* d_ws, size_t ws_size,
                              hipStream_t stream)
{
    const float* x     = (const float*)d_in[0];
    const float* n1g   = (const float*)d_in[1];
    const float* n1b   = (const float*)d_in[2];
    const float* n2g   = (const float*)d_in[3];
    const float* n2b   = (const float*)d_in[4];
    const float* qkvw  = (const float*)d_in[5];
    const float* projw = (const float*)d_in[6];
    const float* projb = (const float*)d_in[7];
    const float* fc1w  = (const float*)d_in[8];
    const float* fc1b  = (const float*)d_in[9];
    const float* fc2w  = (const float*)d_in[10];
    const float* fc2b  = (const float*)d_in[11];
    float* out = (float*)d_out;

    const int total = in_sizes[0];          // B * 16384 * 768
    const int rows  = total / 768;          // 65536 token rows
    const int Smod  = total / 3;            // 2^24 for B=4
    const int Bw    = rows / 64;            // windows
    const int C     = 768;

    bf16* qkv     = (bf16*)d_ws;
    bf16* Ybuf    = qkv + (size_t)rows * 2304;
    bf16* qkvw_b  = Ybuf + (size_t)rows * 768;
    bf16* projw_b = qkvw_b + (size_t)3 * C * C;
    bf16* Pbuf    = qkv;
    // Gbuf lives in d_out scratch (33.5MB << out_size; final_fused fully
    // overwrites out afterwards).
    bf16* Gb      = (bf16*)d_out;

    const int nqkvw  = 3 * C * C;
    const int nprojw = C * C;
    f2b<<<(nqkvw / 4 + 255) / 256, 256, 0, stream>>>(qkvw, qkvw_b, nqkvw);
    f2b<<<(nprojw / 4 + 255) / 256, 256, 0, stream>>>(projw, projw_b, nprojw);

    ln1_win<<<rows / 4, 256, 0, stream>>>(x, n1g, n1b, Ybuf);

    gsum<<<(Smod / 8 + 255) / 256, 256, 0, stream>>>(Ybuf, Gb, Smod);

    const int nbm = rows / 256;             // 256 m-tiles
    gemm8p<1, false><<<nbm * 9, 512, 0, stream>>>(
        nullptr, Ybuf, Gb, qkvw_b, nullptr, qkv, 768, 2304, Smod, 9);

    attn_win<<<Bw * 12, 64, 0, stream>>>(qkv, Ybuf);

    gemm8p<0, true><<<nbm * 3, 512, 0, stream>>>(
        Ybuf, nullptr, nullptr, projw_b, projb, Pbuf, 768, 768, 0, 3);

    final_fused<<<rows / 4, 256, 0, stream>>>(Pbuf, n2g, n2b, fc1w, fc1b,
                                              fc2w, fc2b, out);
}